// Round 1
// baseline (31233.939 us; speedup 1.0000x reference)
//
#include <hip/hip_runtime.h>
#include <hip/hip_fp16.h>

// LSTM: B=128, T=1024, H=768, C=256.
// Plan: 8 groups x 16 batches (group g = bid&7 -> XCD-local), 32 blocks/group,
// 384 thr (6 waves)/block. W_hh persistent in VGPR MFMA B-frags (96 VGPR/lane).
// Per step: stage h (fp16, LDS XOR-swizzled) -> 24 chained mfma_f32_16x16x32_f16
// -> wave-local i/f/g/o regather via padded LDS -> pointwise c/h update ->
// h double-buffered in ws + c_t to fp16 history -> 32-block sense barrier.
// After loop: per-group MFMA FC (M=16 batches, N=256, K=768) from c history.

#define B_ 128
#define T_ 1024
#define H_ 768
#define C_ 256

typedef _Float16 f16;
typedef _Float16 f16x8 __attribute__((ext_vector_type(8)));
typedef float f32x4 __attribute__((ext_vector_type(4)));

__device__ __forceinline__ float sigm_f(float x) {
  return 1.0f / (1.0f + exp2f(-1.4426950408889634f * x));
}
__device__ __forceinline__ float tanh_f(float x) {
  float ax = fabsf(x);
  float e = exp2f(-2.8853900817779268f * ax);   // e^{-2|x|}
  float t = (1.0f - e) / (1.0f + e);
  return copysignf(t, x);
}

__global__ __launch_bounds__(384, 2) void lstm_main(
    const float* __restrict__ x,      // [128][1024]
    const float* __restrict__ w_in,   // [3072]  (W_ih[:,0])
    const float* __restrict__ W_hh,   // [3072][768]
    const float* __restrict__ b_ih,   // [3072]
    const float* __restrict__ b_hh,   // [3072]
    const float* __restrict__ fc_b,   // [256]
    float* __restrict__ out,          // [128][1024][256]
    f16* __restrict__ hbuf,           // [2][128][768] (double-buffered h)
    const f16* __restrict__ fcWh,     // [256][768] fp16
    f16* __restrict__ c_hist,         // [1024][128][768] fp16
    unsigned* __restrict__ bar)       // per-group ctr/gen
{
  __shared__ float4 h_s4[1536];                 // 16 x 768 fp16, swizzled
  __shared__ __align__(16) float gbuf[6 * 320]; // per-wave 16x20 fp32 regather
  char* h_s = (char*)h_s4;

  const int tid = threadIdx.x;
  const int w   = tid >> 6;        // wave 0..5
  const int l   = tid & 63;
  const int bid = blockIdx.x;
  const int g   = bid & 7;         // group -> XCD (round-robin heuristic)
  const int r   = bid >> 3;        // 0..31 within group
  const int bg  = g * 16;          // first batch of group
  const int J0  = r * 24;          // first h-column of block
  const int n   = l & 15;          // fragment row index
  const int hi  = l >> 4;          // k-slice group 0..3

  // B-fragment row: n -> (jl = n>>2, tau = n&3); gate row = tau*768 + (J0+4w+jl)
  const int jl  = n >> 2, tau = n & 3;
  const int jp_n = J0 + (w << 2) + jl;
  const float* wr = W_hh + (size_t)(tau * H_ + jp_n) * H_;

  // Persistent W_hh fragments (fp16), 24 x f16x8 = 96 VGPR
  f16x8 wfrag[24];
#pragma unroll
  for (int ks = 0; ks < 24; ++ks) {
    const int k0 = ks * 32 + hi * 8;
    f16x8 f;
#pragma unroll
    for (int e = 0; e < 8; ++e) f[e] = (f16)wr[k0 + e];
    wfrag[ks] = f;
  }

  // Pointwise lane ownership: (b_own, jj) one (batch, h-col) pair per lane
  const int b_own = l & 15;
  const int jj    = hi;                   // 0..3
  const int jp_own = J0 + (w << 2) + jj;
  float win4[4], bias4[4];
#pragma unroll
  for (int t4 = 0; t4 < 4; ++t4) {
    const int row = t4 * H_ + jp_own;
    win4[t4]  = w_in[row];
    bias4[t4] = b_ih[row] + b_hh[row];
  }
  const float* xrow = x + (size_t)(bg + b_own) * T_;

  float c = 0.0f;
  float* gw = gbuf + w * 320;
  unsigned* ctr = bar + g * 16;
  unsigned* gen = bar + g * 16 + 8;

  for (int t = 0; t < T_; ++t) {
    // ---- stage h_{t-1} (hbuf[t&1], group slice) into LDS, XOR-swizzled ----
    const f16* hsrc = hbuf + (size_t)(t & 1) * (B_ * H_) + (size_t)bg * H_;
#pragma unroll
    for (int s = 0; s < 4; ++s) {
      const int ci = tid + 384 * s;       // 1536 16B-chunks total
      const int bb = ci / 96, ck = ci - bb * 96;
      float4 v = *(const float4*)(hsrc + bb * H_ + ck * 8);
      *(float4*)(h_s + bb * 1536 + ((ck ^ (bb & 7)) << 4)) = v;
    }
    __syncthreads();

    // ---- gates = h @ W^T : 24 K-steps, 2 interleaved accumulators ----
    f32x4 acc0 = {0.f, 0.f, 0.f, 0.f}, acc1 = {0.f, 0.f, 0.f, 0.f};
#pragma unroll
    for (int ks = 0; ks < 24; ++ks) {
      f16x8 a = *(const f16x8*)(h_s + (l & 15) * 1536 +
                                ((((ks << 2) + hi) ^ (l & 7)) << 4));
      if (ks & 1) acc1 = __builtin_amdgcn_mfma_f32_16x16x32_f16(a, wfrag[ks], acc1, 0, 0, 0);
      else        acc0 = __builtin_amdgcn_mfma_f32_16x16x32_f16(a, wfrag[ks], acc0, 0, 0, 0);
    }
    f32x4 acc = acc0 + acc1;

    // ---- wave-local regather: D(lane,q) = gates[b=hi*4+q][n] -> gw[b][n] ----
#pragma unroll
    for (int q = 0; q < 4; ++q)
      gw[(hi * 4 + q) * 20 + n] = acc[q];   // pad 20 avoids bank conflicts
    float4 gv = *(const float4*)(gw + b_own * 20 + jj * 4);  // i,f,g,o

    // ---- pointwise ----
    const float xt = xrow[t];
    const float gi = gv.x + xt * win4[0] + bias4[0];
    const float gf = gv.y + xt * win4[1] + bias4[1];
    const float gg = gv.z + xt * win4[2] + bias4[2];
    const float go = gv.w + xt * win4[3] + bias4[3];
    c = sigm_f(gf) * c + sigm_f(gi) * tanh_f(gg);
    const float h = sigm_f(go) * tanh_f(c);

    hbuf[(size_t)((t + 1) & 1) * (B_ * H_) + (size_t)(bg + b_own) * H_ + jp_own] = (f16)h;
    c_hist[((size_t)t * B_ + bg + b_own) * H_ + jp_own] = (f16)c;

    // ---- 32-block group barrier (sense-reversing, device-scope) ----
    __syncthreads();
    if (tid == 0) {
      __threadfence();
      unsigned g0 = __hip_atomic_load(gen, __ATOMIC_ACQUIRE, __HIP_MEMORY_SCOPE_AGENT);
      unsigned a  = __hip_atomic_fetch_add(ctr, 1u, __ATOMIC_ACQ_REL, __HIP_MEMORY_SCOPE_AGENT);
      if (a == 31u) {
        __hip_atomic_store(ctr, 0u, __ATOMIC_RELAXED, __HIP_MEMORY_SCOPE_AGENT);
        __hip_atomic_fetch_add(gen, 1u, __ATOMIC_RELEASE, __HIP_MEMORY_SCOPE_AGENT);
      } else {
        while (__hip_atomic_load(gen, __ATOMIC_ACQUIRE, __HIP_MEMORY_SCOPE_AGENT) == g0) {
          __builtin_amdgcn_s_sleep(1);
        }
      }
      __threadfence();
    }
    __syncthreads();
  }

  // ---- FC: out[b,t,:] = c_t[b,:] @ fcW^T + fc_b (per group, no sync needed) ----
  for (int ti = w; ti < 32; ti += 6) {
    const int t = r + 32 * ti;
    const f16* ar = c_hist + ((size_t)t * B_ + bg + n) * H_;  // A row = batch n
    f16x8 afrag[24];
#pragma unroll
    for (int ks = 0; ks < 24; ++ks)
      afrag[ks] = *(const f16x8*)(ar + ks * 32 + hi * 8);
    for (int nt = 0; nt < 16; ++nt) {
      f32x4 fa = {0.f, 0.f, 0.f, 0.f};
      const f16* br = fcWh + (size_t)(nt * 16 + n) * H_;
#pragma unroll
      for (int ks = 0; ks < 24; ++ks) {
        f16x8 bfr = *(const f16x8*)(br + ks * 32 + hi * 8);
        fa = __builtin_amdgcn_mfma_f32_16x16x32_f16(afrag[ks], bfr, fa, 0, 0, 0);
      }
      const float fb = fc_b[nt * 16 + n];
      float* ob = out + (size_t)t * C_ + nt * 16 + n;
#pragma unroll
      for (int q = 0; q < 4; ++q)
        ob[(size_t)(bg + hi * 4 + q) * ((size_t)T_ * C_)] = fa[q] + fb;
    }
  }
}

__global__ __launch_bounds__(256) void prep(
    const float* __restrict__ fcW, f16* __restrict__ fcWh,
    f16* __restrict__ hbuf, unsigned* __restrict__ bar)
{
  const int i = blockIdx.x * 256 + threadIdx.x;
  const int nth = gridDim.x * 256;
  for (int k = i; k < C_ * H_; k += nth) fcWh[k] = (f16)fcW[k];
  for (int k = i; k < 2 * B_ * H_; k += nth) hbuf[k] = (f16)0.0f;
  if (i < 128) bar[i] = 0u;
}

extern "C" void kernel_launch(void* const* d_in, const int* in_sizes, int n_in,
                              void* d_out, int out_size, void* d_ws, size_t ws_size,
                              hipStream_t stream) {
  const float* x   = (const float*)d_in[0];
  const float* Wih = (const float*)d_in[1];   // [3072][1] == w_in
  const float* Whh = (const float*)d_in[2];
  const float* bih = (const float*)d_in[3];
  const float* bhh = (const float*)d_in[4];
  const float* fcW = (const float*)d_in[5];
  const float* fcb = (const float*)d_in[6];
  float* out = (float*)d_out;

  char* ws = (char*)d_ws;
  f16* hbuf      = (f16*)ws;                   // 393216 B
  f16* fcWh      = (f16*)(ws + 393216);        // 393216 B
  unsigned* bar  = (unsigned*)(ws + 786432);   // 512 B
  f16* c_hist    = (f16*)(ws + (1 << 20));     // 201326592 B
  const size_t need = (size_t)(1 << 20) + 201326592ull;
  if (ws_size < need) {  // ws too small: deterministic zero output (absmax 0.1216 signature)
    hipMemsetAsync(d_out, 0, (size_t)out_size * 4, stream);
    return;
  }

  hipLaunchKernelGGL(prep, dim3(256), dim3(256), 0, stream, fcW, fcWh, hbuf, bar);

  void* args[] = { (void*)&x, (void*)&Wih, (void*)&Whh, (void*)&bih, (void*)&bhh,
                   (void*)&fcb, (void*)&out, (void*)&hbuf, (void*)&fcWh,
                   (void*)&c_hist, (void*)&bar };
  hipLaunchCooperativeKernel((void*)lstm_main, dim3(256), dim3(384), args, 0, stream);
}

// Round 3
// 2866.662 us; speedup vs baseline: 10.8956x; 10.8956x over previous
//
#include <hip/hip_runtime.h>
#include <hip/hip_fp16.h>

// LSTM: B=128, T=1024, H=768, C=256.
// Round 3: XCD-local groups (XCC_ID registration, 1 block/CU via LDS pad) with
// a RELAXED agent-scope barrier: fetch_add + spin load both compile to sc1 ops
// at the device coherence point (live by construction), NO acquire/release
// cache maintenance (that was round-1's 30us/step wbl2 storm). Data coherence
// inside an XCD: write-through L1 + vmcnt(0) drain at __syncthreads + sc0
// (L1-bypass) reads. Every spin has a watchdog -> deadlock fails fast with
// counters instead of a 600s timeout. Safe fallback = round-1 proven barrier.

#define B_ 128
#define T_ 1024
#define H_ 768
#define C_ 256

typedef _Float16 f16;
typedef _Float16 f16x8 __attribute__((ext_vector_type(8)));
typedef float f32x4 __attribute__((ext_vector_type(4)));

#define SPIN_CAP 3000000u

__device__ __forceinline__ float sigm_f(float x) {
  return 1.0f / (1.0f + exp2f(-1.4426950408889634f * x));
}
__device__ __forceinline__ float tanh_f(float x) {
  float ax = fabsf(x);
  float e = exp2f(-2.8853900817779268f * ax);   // e^{-2|x|}
  float t = (1.0f - e) / (1.0f + e);
  return copysignf(t, x);
}

__global__ __launch_bounds__(384, 2) void lstm_main(
    const float* __restrict__ x,      // [128][1024]
    const float* __restrict__ w_in,   // [3072]  (W_ih[:,0])
    const float* __restrict__ W_hh,   // [3072][768]
    const float* __restrict__ b_ih,   // [3072]
    const float* __restrict__ b_hh,   // [3072]
    const float* __restrict__ fc_b,   // [256]
    float* __restrict__ out,          // [128][1024][256]
    f16* __restrict__ hbuf,           // [2][128][768] (double-buffered h)
    const f16* __restrict__ fcWh,     // [256][768] fp16
    f16* __restrict__ c_hist,         // [1024][128][768] fp16
    unsigned* __restrict__ bar)       // [0..7]=pool [15]=regctr [32+g*32]=fast ctr [512+g*16(+8)]=safe
{
  __shared__ float4 h_s4[1536];                 // 16 x 768 fp16, swizzled
  __shared__ __align__(16) float gbuf[6 * 320]; // per-wave 16x20 fp32 regather
  __shared__ float pad_f[13056];                // 52KB pad: forces 1 block/CU
  __shared__ int s_g, s_r, s_mode, s_dead;
  char* h_s = (char*)h_s4;

  const int tid = threadIdx.x;
  const int w   = tid >> 6;        // wave 0..5
  const int l   = tid & 63;
  const int bid = blockIdx.x;

  // keep the LDS pad alive
  asm volatile("" :: "v"(pad_f[tid & 1023]));

  // ---- registration: group = physical XCD (L2-pure by construction) ----
  if (tid == 0) {
    s_dead = 0;
    unsigned xcc;
    asm volatile("s_getreg_b32 %0, hwreg(20, 0, 32)" : "=s"(xcc));  // HW_REG_XCC_ID
    xcc &= 7u;
    unsigned slot = atomicAdd(&bar[xcc], 1u);
    s_g = (int)xcc;
    s_r = (int)(slot & 31u);
    int bad = (slot >= 32u) ? 1 : 0;
    __threadfence();
    atomicAdd(&bar[15], 1u);   // grid-wide registration barrier (monotonic)
    unsigned it = 0;
    while (__hip_atomic_load(&bar[15], __ATOMIC_ACQUIRE, __HIP_MEMORY_SCOPE_AGENT) < 256u) {
      __builtin_amdgcn_s_sleep(2);
      if (++it > SPIN_CAP) { bad = 1; break; }
    }
    __threadfence();
#pragma unroll
    for (int i2 = 0; i2 < 8; ++i2)
      if (__hip_atomic_load(&bar[i2], __ATOMIC_RELAXED, __HIP_MEMORY_SCOPE_AGENT) != 32u) bad = 1;
    s_mode = bad;
  }
  __syncthreads();
  const int mode = s_mode;         // 0 = fast (XCD-pure groups), 1 = safe fallback
  int g, r;
  if (mode) { g = bid & 7; r = bid >> 3; } else { g = s_g; r = s_r; }

  const int bg  = g * 16;          // first batch of group
  const int J0  = r * 24;          // first h-column of block
  const int n   = l & 15;          // fragment row index
  const int hi  = l >> 4;          // k-slice group 0..3

  // B-fragment row: n -> (jl = n>>2, tau = n&3); gate row = tau*768 + (J0+4w+jl)
  const int jl  = n >> 2, tau = n & 3;
  const int jp_n = J0 + (w << 2) + jl;
  const float* wr = W_hh + (size_t)(tau * H_ + jp_n) * H_;

  // Persistent W_hh fragments (fp16), 24 x f16x8 = 96 VGPR
  f16x8 wfrag[24];
#pragma unroll
  for (int ks = 0; ks < 24; ++ks) {
    const int k0 = ks * 32 + hi * 8;
    f16x8 f;
#pragma unroll
    for (int e = 0; e < 8; ++e) f[e] = (f16)wr[k0 + e];
    wfrag[ks] = f;
  }

  // Pointwise lane ownership: (b_own, jj) one (batch, h-col) pair per lane
  const int b_own = l & 15;
  const int jj    = hi;
  const int jp_own = J0 + (w << 2) + jj;
  float win4[4], bias4[4];
#pragma unroll
  for (int t4 = 0; t4 < 4; ++t4) {
    const int row = t4 * H_ + jp_own;
    win4[t4]  = w_in[row];
    bias4[t4] = b_ih[row] + b_hh[row];
  }
  const float* xrow = x + (size_t)(bg + b_own) * T_;

  float c = 0.0f;
  float* gw = gbuf + w * 320;
  unsigned* fctr = bar + 32 + g * 32;            // fast: monotonic, MALL via sc1
  unsigned* ctr  = bar + 512 + g * 16;           // safe: round-1 sense barrier
  unsigned* gen  = bar + 512 + g * 16 + 8;

  for (int t = 0; t < T_; ++t) {
    // ---- stage h_{t-1} (hbuf[t&1], group slice) into LDS, XOR-swizzled ----
    const f16* hsrc = hbuf + (size_t)(t & 1) * (B_ * H_) + (size_t)bg * H_;
    const float* gp[4]; int ldst[4]; float4 gv4[4];
#pragma unroll
    for (int s = 0; s < 4; ++s) {
      const int ci = tid + 384 * s;       // 1536 16B-chunks total
      const int bb = ci / 96, ck = ci - bb * 96;
      gp[s]   = (const float*)(hsrc + bb * H_ + ck * 8);
      ldst[s] = bb * 1536 + ((ck ^ (bb & 7)) << 4);
    }
    if (!mode) {
      // sc0 = L1-bypass: read fresh data from the XCD-local L2
      asm volatile(
        "global_load_dwordx4 %0, %4, off sc0\n\t"
        "global_load_dwordx4 %1, %5, off sc0\n\t"
        "global_load_dwordx4 %2, %6, off sc0\n\t"
        "global_load_dwordx4 %3, %7, off sc0\n\t"
        "s_waitcnt vmcnt(0)"
        : "=&v"(gv4[0]), "=&v"(gv4[1]), "=&v"(gv4[2]), "=&v"(gv4[3])
        : "v"(gp[0]), "v"(gp[1]), "v"(gp[2]), "v"(gp[3])
        : "memory");
    } else {
#pragma unroll
      for (int s = 0; s < 4; ++s) gv4[s] = *(const float4*)gp[s];
    }
#pragma unroll
    for (int s = 0; s < 4; ++s) *(float4*)(h_s + ldst[s]) = gv4[s];
    __syncthreads();

    // ---- gates = h @ W^T : 24 K-steps, 2 interleaved accumulators ----
    f32x4 acc0 = {0.f, 0.f, 0.f, 0.f}, acc1 = {0.f, 0.f, 0.f, 0.f};
#pragma unroll
    for (int ks = 0; ks < 24; ++ks) {
      f16x8 a = *(const f16x8*)(h_s + (l & 15) * 1536 +
                                ((((ks << 2) + hi) ^ (l & 7)) << 4));
      if (ks & 1) acc1 = __builtin_amdgcn_mfma_f32_16x16x32_f16(a, wfrag[ks], acc1, 0, 0, 0);
      else        acc0 = __builtin_amdgcn_mfma_f32_16x16x32_f16(a, wfrag[ks], acc0, 0, 0, 0);
    }
    f32x4 acc = acc0 + acc1;

    // ---- wave-local regather: D(lane,q) = gates[b=hi*4+q][n] -> gw[b][n] ----
#pragma unroll
    for (int q = 0; q < 4; ++q)
      gw[(hi * 4 + q) * 20 + n] = acc[q];
    float4 gv = *(const float4*)(gw + b_own * 20 + jj * 4);  // i,f,g,o

    // ---- pointwise ----
    const float xt = xrow[t];
    const float gi = gv.x + xt * win4[0] + bias4[0];
    const float gf = gv.y + xt * win4[1] + bias4[1];
    const float gg = gv.z + xt * win4[2] + bias4[2];
    const float go = gv.w + xt * win4[3] + bias4[3];
    c = sigm_f(gf) * c + sigm_f(gi) * tanh_f(gg);
    const float h = sigm_f(go) * tanh_f(c);

    hbuf[(size_t)((t + 1) & 1) * (B_ * H_) + (size_t)(bg + b_own) * H_ + jp_own] = (f16)h;
    c_hist[((size_t)t * B_ + bg + b_own) * H_ + jp_own] = (f16)c;

    // ---- group barrier ----
    __syncthreads();   // compiler drains vmcnt(0): block's stores are ACKed in local L2
    if (tid == 0) {
      if (!mode) {
        // RELAXED agent atomics: add + load both sc1 (same coherence point,
        // live), no wbl2/inv cache maintenance (cheap).
        __hip_atomic_fetch_add(fctr, 1u, __ATOMIC_RELAXED, __HIP_MEMORY_SCOPE_AGENT);
        const unsigned target = 32u * (unsigned)(t + 1);
        unsigned it = 0;
        while (__hip_atomic_load(fctr, __ATOMIC_RELAXED, __HIP_MEMORY_SCOPE_AGENT) < target) {
          __builtin_amdgcn_s_sleep(1);
          if (++it > SPIN_CAP) { s_dead = 1; break; }
        }
      } else {
        // safe fallback: round-1 heavy agent-scope sense barrier
        __threadfence();
        unsigned g0 = __hip_atomic_load(gen, __ATOMIC_ACQUIRE, __HIP_MEMORY_SCOPE_AGENT);
        unsigned a  = __hip_atomic_fetch_add(ctr, 1u, __ATOMIC_ACQ_REL, __HIP_MEMORY_SCOPE_AGENT);
        if (a == 31u) {
          __hip_atomic_store(ctr, 0u, __ATOMIC_RELAXED, __HIP_MEMORY_SCOPE_AGENT);
          __hip_atomic_fetch_add(gen, 1u, __ATOMIC_RELEASE, __HIP_MEMORY_SCOPE_AGENT);
        } else {
          unsigned it = 0;
          while (__hip_atomic_load(gen, __ATOMIC_ACQUIRE, __HIP_MEMORY_SCOPE_AGENT) == g0) {
            __builtin_amdgcn_s_sleep(1);
            if (++it > SPIN_CAP) { s_dead = 1; break; }
          }
        }
        __threadfence();
      }
    }
    __syncthreads();
    if (s_dead) return;   // watchdog tripped: fail fast (visible), don't hang
  }

  // ---- FC: out[b,t,:] = c_t[b,:] @ fcW^T + fc_b (per group) ----
  for (int ti = w; ti < 32; ti += 6) {
    const int tt = r + 32 * ti;
    const f16* ar = c_hist + ((size_t)tt * B_ + bg + n) * H_;  // A row = batch n
    const f16* ab = ar + hi * 8;
    f16x8 afrag[24];
    if (!mode) {
#pragma unroll
      for (int kg = 0; kg < 3; ++kg) {
        asm volatile(
          "global_load_dwordx4 %0, %8, off sc0\n\t"
          "global_load_dwordx4 %1, %8, off offset:64 sc0\n\t"
          "global_load_dwordx4 %2, %8, off offset:128 sc0\n\t"
          "global_load_dwordx4 %3, %8, off offset:192 sc0\n\t"
          "global_load_dwordx4 %4, %8, off offset:256 sc0\n\t"
          "global_load_dwordx4 %5, %8, off offset:320 sc0\n\t"
          "global_load_dwordx4 %6, %8, off offset:384 sc0\n\t"
          "global_load_dwordx4 %7, %8, off offset:448 sc0\n\t"
          "s_waitcnt vmcnt(0)"
          : "=&v"(afrag[kg * 8 + 0]), "=&v"(afrag[kg * 8 + 1]),
            "=&v"(afrag[kg * 8 + 2]), "=&v"(afrag[kg * 8 + 3]),
            "=&v"(afrag[kg * 8 + 4]), "=&v"(afrag[kg * 8 + 5]),
            "=&v"(afrag[kg * 8 + 6]), "=&v"(afrag[kg * 8 + 7])
          : "v"(ab + kg * 256)
          : "memory");
      }
    } else {
#pragma unroll
      for (int ks = 0; ks < 24; ++ks)
        afrag[ks] = *(const f16x8*)(ar + ks * 32 + hi * 8);
    }
    for (int nt = 0; nt < 16; ++nt) {
      f32x4 fa = {0.f, 0.f, 0.f, 0.f};
      const f16* br = fcWh + (size_t)(nt * 16 + n) * H_;
#pragma unroll
      for (int ks = 0; ks < 24; ++ks) {
        f16x8 bfr = *(const f16x8*)(br + ks * 32 + hi * 8);
        fa = __builtin_amdgcn_mfma_f32_16x16x32_f16(afrag[ks], bfr, fa, 0, 0, 0);
      }
      const float fb = fc_b[nt * 16 + n];
      float* ob = out + (size_t)tt * C_ + nt * 16 + n;
#pragma unroll
      for (int q = 0; q < 4; ++q)
        ob[(size_t)(bg + hi * 4 + q) * ((size_t)T_ * C_)] = fa[q] + fb;
    }
  }
}

__global__ __launch_bounds__(256) void prep(
    const float* __restrict__ fcW, f16* __restrict__ fcWh,
    f16* __restrict__ hbuf, unsigned* __restrict__ bar)
{
  const int i = blockIdx.x * 256 + threadIdx.x;
  const int nth = gridDim.x * 256;
  for (int k = i; k < C_ * H_; k += nth) fcWh[k] = (f16)fcW[k];
  for (int k = i; k < 2 * B_ * H_; k += nth) hbuf[k] = (f16)0.0f;
  if (i < 1024) bar[i] = 0u;
}

extern "C" void kernel_launch(void* const* d_in, const int* in_sizes, int n_in,
                              void* d_out, int out_size, void* d_ws, size_t ws_size,
                              hipStream_t stream) {
  const float* x   = (const float*)d_in[0];
  const float* Wih = (const float*)d_in[1];   // [3072][1] == w_in
  const float* Whh = (const float*)d_in[2];
  const float* bih = (const float*)d_in[3];
  const float* bhh = (const float*)d_in[4];
  const float* fcW = (const float*)d_in[5];
  const float* fcb = (const float*)d_in[6];
  float* out = (float*)d_out;

  char* ws = (char*)d_ws;
  f16* hbuf      = (f16*)ws;                   // 393216 B
  f16* fcWh      = (f16*)(ws + 393216);        // 393216 B
  unsigned* bar  = (unsigned*)(ws + 786432);   // 4096 B
  f16* c_hist    = (f16*)(ws + (1 << 20));     // 201326592 B
  const size_t need = (size_t)(1 << 20) + 201326592ull;
  if (ws_size < need) {
    hipMemsetAsync(d_out, 0, (size_t)out_size * 4, stream);
    return;
  }

  hipLaunchKernelGGL(prep, dim3(256), dim3(256), 0, stream, fcW, fcWh, hbuf, bar);

  void* args[] = { (void*)&x, (void*)&Wih, (void*)&Whh, (void*)&bih, (void*)&bhh,
                   (void*)&fcb, (void*)&out, (void*)&hbuf, (void*)&fcWh,
                   (void*)&c_hist, (void*)&bar };
  hipLaunchCooperativeKernel((void*)lstm_main, dim3(256), dim3(384), args, 0, stream);
}